// Round 9
// baseline (1261.739 us; speedup 1.0000x reference)
//
#include <hip/hip_runtime.h>

// B=2, L=2048, E=1024, H=16, d=64.
// d_out: out [4096][1024] fp32, attn [32][2048][2048] fp32.
// Workspace (48 MB): qk_ws bf16[4096][2048] | vt_ws bf16[32][64][2048] |
//   ao_ws bf16[4096][1024] | xb bf16[4096][1024] | wqkvb bf16[3072][1024] | woutb bf16[1024][1024]

typedef __attribute__((ext_vector_type(8))) short bf16x8;
typedef __attribute__((ext_vector_type(4))) float f32x4;

__device__ __forceinline__ unsigned short f2bf(float f) {
  unsigned int u = __float_as_uint(f);
  u += 0x7fffu + ((u >> 16) & 1u);   // RNE
  return (unsigned short)(u >> 16);
}

// ---- K0: one-shot fp32 -> bf16 conversion of x, w_qkv, w_out ----
__global__ __launch_bounds__(256) void conv_bf16(
    const float* __restrict__ X, const float* __restrict__ Wqkv, const float* __restrict__ Wout,
    unsigned short* __restrict__ xb, unsigned short* __restrict__ wqkvb,
    unsigned short* __restrict__ woutb) {
  size_t e0 = ((size_t)blockIdx.x * 256 + threadIdx.x) * 8;
  const float* src; unsigned short* dst; size_t off;
  if (e0 < 4194304)      { src = X;    dst = xb;    off = e0; }
  else if (e0 < 7340032) { src = Wqkv; dst = wqkvb; off = e0 - 4194304; }
  else                   { src = Wout; dst = woutb; off = e0 - 7340032; }
  float4 a = *(const float4*)(src + off);
  float4 c = *(const float4*)(src + off + 4);
  int4 o;
  o.x = f2bf(a.x) | ((unsigned int)f2bf(a.y) << 16);
  o.y = f2bf(a.z) | ((unsigned int)f2bf(a.w) << 16);
  o.z = f2bf(c.x) | ((unsigned int)f2bf(c.y) << 16);
  o.w = f2bf(c.z) | ((unsigned int)f2bf(c.w) << 16);
  *(int4*)(dst + off) = o;
}

// ---- K1: qkv = xb @ wqkvb^T (M=4096, N=3072, K=1024) ----
__global__ __launch_bounds__(256) void gemm_qkv(
    const unsigned short* __restrict__ XB, const unsigned short* __restrict__ WB,
    unsigned short* __restrict__ qk_ws, unsigned short* __restrict__ vt_ws) {
  __shared__ unsigned short smem[2 * 128 * 72];
  unsigned short* a_lds = smem;
  unsigned short* b_lds = smem + 128 * 72;
  const int tid = threadIdx.x;
  const int lane = tid & 63;
  const int wid = tid >> 6;
  const int wm = wid >> 1, wn = wid & 1;
  const int m0 = blockIdx.x * 128;
  const int n0 = blockIdx.y * 128;

  f32x4 acc[4][4];
#pragma unroll
  for (int i = 0; i < 4; ++i)
#pragma unroll
    for (int j = 0; j < 4; ++j) acc[i][j] = (f32x4){0.f, 0.f, 0.f, 0.f};

  for (int kt = 0; kt < 16; ++kt) {
    const int k0 = kt * 64;
#pragma unroll
    for (int i = 0; i < 4; ++i) {
      int c = i * 256 + tid;
      int row = c >> 3, cc = (c & 7) << 3;
      *(int4*)&a_lds[row * 72 + cc] = *(const int4*)(XB + (size_t)(m0 + row) * 1024 + k0 + cc);
      *(int4*)&b_lds[row * 72 + cc] = *(const int4*)(WB + (size_t)(n0 + row) * 1024 + k0 + cc);
    }
    __syncthreads();
#pragma unroll
    for (int ks = 0; ks < 2; ++ks) {
      bf16x8 af[4], bfr[4];
#pragma unroll
      for (int f = 0; f < 4; ++f) {
        af[f]  = *(const bf16x8*)&a_lds[(wm * 64 + f * 16 + (lane & 15)) * 72 + ks * 32 + (lane >> 4) * 8];
        bfr[f] = *(const bf16x8*)&b_lds[(wn * 64 + f * 16 + (lane & 15)) * 72 + ks * 32 + (lane >> 4) * 8];
      }
#pragma unroll
      for (int fi = 0; fi < 4; ++fi)
#pragma unroll
        for (int fj = 0; fj < 4; ++fj)
          acc[fi][fj] = __builtin_amdgcn_mfma_f32_16x16x32_bf16(af[fi], bfr[fj], acc[fi][fj], 0, 0, 0);
    }
    __syncthreads();
  }

  if (n0 < 2048) {
#pragma unroll
    for (int fi = 0; fi < 4; ++fi)
#pragma unroll
      for (int fj = 0; fj < 4; ++fj) {
        int row = wm * 64 + fi * 16 + ((lane >> 4) << 2);
        int col = wn * 64 + fj * 16 + (lane & 15);
#pragma unroll
        for (int r = 0; r < 4; ++r) smem[(row + r) * 136 + col] = f2bf(acc[fi][fj][r]);
      }
    __syncthreads();
#pragma unroll
    for (int i = 0; i < 8; ++i) {
      int c = i * 256 + tid;
      int row = c >> 4, cc = c & 15;
      *(int4*)(qk_ws + (size_t)(m0 + row) * 2048 + n0 + cc * 8) = *(const int4*)&smem[row * 136 + cc * 8];
    }
  } else {
#pragma unroll
    for (int fi = 0; fi < 4; ++fi)
#pragma unroll
      for (int fj = 0; fj < 4; ++fj) {
        int colg = n0 - 2048 + wn * 64 + fj * 16 + (lane & 15);
        int tok = m0 + wm * 64 + fi * 16 + ((lane >> 4) << 2);
        int bb = tok >> 11, lt = tok & 2047;
        int bh = bb * 16 + (colg >> 6);
        int dd = colg & 63;
        unsigned int p0 = f2bf(acc[fi][fj][0]) | ((unsigned int)f2bf(acc[fi][fj][1]) << 16);
        unsigned int p1 = f2bf(acc[fi][fj][2]) | ((unsigned int)f2bf(acc[fi][fj][3]) << 16);
        *(uint2*)(vt_ws + (size_t)(bh * 64 + dd) * 2048 + lt) = make_uint2(p0, p1);
      }
  }
}

// ---- K2: fused attention, QBLK=64, direct-global K/V fragments, e-only LDS ----
__global__ __launch_bounds__(256) void attn_fused(
    const unsigned short* __restrict__ qk_ws, const unsigned short* __restrict__ vt_ws,
    float* __restrict__ attn_out, unsigned short* __restrict__ ao_ws) {
  __shared__ unsigned short e_lds[2][64 * 72];
  __shared__ float ls_rs[64];
  __shared__ float ls_inv[64];

  const int tid = threadIdx.x;
  const int lane = tid & 63;
  const int w = tid >> 6;
  const int l15 = lane & 15;
  const int l4 = lane >> 4;
  const int bh = blockIdx.y;
  const int b = bh >> 4;
  const int h = bh & 15;
  const int q0 = blockIdx.x * 64;

  // K fragment pointer: row j = jt*64 + w*16 + l15, k-slice (d) = ks*32 + l4*8
  const unsigned short* kp = qk_ws + ((size_t)(b * 2048 + w * 16 + l15)) * 2048 + 1024 + h * 64 + l4 * 8;
  const size_t KJ = (size_t)64 * 2048;   // j-tile step (64 rows)
  // V fragment pointer: row d = w*16 + l15, k-slice (j) = jt*64 + ks*32 + l4*8
  const unsigned short* vp = vt_ws + ((size_t)(bh * 64 + w * 16 + l15)) * 2048 + l4 * 8;

  // Q fragments (held all kernel): q row = q0 + fi*16 + l15, k (d) = ks*32 + l4*8
  bf16x8 qf[4][2];
#pragma unroll
  for (int fi = 0; fi < 4; ++fi)
#pragma unroll
    for (int ks = 0; ks < 2; ++ks)
      qf[fi][ks] = *(const bf16x8*)(qk_ws + ((size_t)(b * 2048 + q0 + fi * 16 + l15)) * 2048 + h * 64 + ks * 32 + l4 * 8);

  // ================= phase 1: rowsums (no barriers) =================
  float ps[4][4];
#pragma unroll
  for (int fi = 0; fi < 4; ++fi)
#pragma unroll
    for (int r = 0; r < 4; ++r) ps[fi][r] = 0.f;

  bf16x8 kn0 = *(const bf16x8*)(kp);
  bf16x8 kn1 = *(const bf16x8*)(kp + 32);
  for (int jt = 0; jt < 32; ++jt) {
    bf16x8 kc0 = kn0, kc1 = kn1;
    if (jt + 1 < 32) {
      kn0 = *(const bf16x8*)(kp + (jt + 1) * KJ);
      kn1 = *(const bf16x8*)(kp + (jt + 1) * KJ + 32);
    }
    f32x4 s[4];
#pragma unroll
    for (int fi = 0; fi < 4; ++fi) {
      s[fi] = (f32x4){0.f, 0.f, 0.f, 0.f};
      s[fi] = __builtin_amdgcn_mfma_f32_16x16x32_bf16(qf[fi][0], kc0, s[fi], 0, 0, 0);
      s[fi] = __builtin_amdgcn_mfma_f32_16x16x32_bf16(qf[fi][1], kc1, s[fi], 0, 0, 0);
    }
#pragma unroll
    for (int fi = 0; fi < 4; ++fi)
#pragma unroll
      for (int r = 0; r < 4; ++r) ps[fi][r] += __expf(s[fi][r] * 0.125f);
  }

  if (tid < 64) ls_rs[tid] = 0.f;
  __syncthreads();
#pragma unroll
  for (int fi = 0; fi < 4; ++fi)
#pragma unroll
    for (int r = 0; r < 4; ++r) {
      float v = ps[fi][r];
      v += __shfl_xor(v, 1);
      v += __shfl_xor(v, 2);
      v += __shfl_xor(v, 4);
      v += __shfl_xor(v, 8);
      if (l15 == 0) atomicAdd(&ls_rs[fi * 16 + l4 * 4 + r], v);
    }
  __syncthreads();
  if (tid < 64) ls_inv[tid] = 1.0f / ls_rs[tid];
  __syncthreads();
  float inv_col[4];
#pragma unroll
  for (int mf = 0; mf < 4; ++mf) inv_col[mf] = ls_inv[mf * 16 + l15];

  // ================= phase 2: attn store + PV, double-buffered e_lds =================
  f32x4 pv[4];
#pragma unroll
  for (int mf = 0; mf < 4; ++mf) pv[mf] = (f32x4){0.f, 0.f, 0.f, 0.f};

  const int srow = tid >> 2;          // store: 4 threads/row, 16 cols each
  const int sc0 = (tid & 3) << 4;
  const float siv = ls_inv[srow];

  kn0 = *(const bf16x8*)(kp);
  kn1 = *(const bf16x8*)(kp + 32);
  bf16x8 vn0 = *(const bf16x8*)(vp);
  bf16x8 vn1 = *(const bf16x8*)(vp + 32);
  for (int jt = 0; jt < 32; ++jt) {
    const int cur = jt & 1;
    bf16x8 kc0 = kn0, kc1 = kn1, vc0 = vn0, vc1 = vn1;
    if (jt + 1 < 32) {
      kn0 = *(const bf16x8*)(kp + (jt + 1) * KJ);
      kn1 = *(const bf16x8*)(kp + (jt + 1) * KJ + 32);
      vn0 = *(const bf16x8*)(vp + (jt + 1) * 64);
      vn1 = *(const bf16x8*)(vp + (jt + 1) * 64 + 32);
    }
    f32x4 s[4];
#pragma unroll
    for (int fi = 0; fi < 4; ++fi) {
      s[fi] = (f32x4){0.f, 0.f, 0.f, 0.f};
      s[fi] = __builtin_amdgcn_mfma_f32_16x16x32_bf16(qf[fi][0], kc0, s[fi], 0, 0, 0);
      s[fi] = __builtin_amdgcn_mfma_f32_16x16x32_bf16(qf[fi][1], kc1, s[fi], 0, 0, 0);
    }
    // unnormalized e -> e_lds[cur]  (row m, col j-local)
#pragma unroll
    for (int fi = 0; fi < 4; ++fi) {
      int row0 = fi * 16 + l4 * 4;
      int col = w * 16 + l15;
#pragma unroll
      for (int r = 0; r < 4; ++r)
        e_lds[cur][(row0 + r) * 72 + col] = f2bf(__expf(s[fi][r] * 0.125f));
    }
    __syncthreads();
    // coalesced NT store of normalized attn tile (64 rows x 64 cols)
    {
      int4 raw0 = *(const int4*)&e_lds[cur][srow * 72 + sc0];
      int4 raw1 = *(const int4*)&e_lds[cur][srow * 72 + sc0 + 8];
      size_t ab = ((size_t)bh * 2048 + q0 + srow) * 2048 + jt * 64 + sc0;
      f32x4 o;
      o.x = __uint_as_float(((unsigned int)raw0.x) << 16) * siv;
      o.y = __uint_as_float(((unsigned int)raw0.x) & 0xffff0000u) * siv;
      o.z = __uint_as_float(((unsigned int)raw0.y) << 16) * siv;
      o.w = __uint_as_float(((unsigned int)raw0.y) & 0xffff0000u) * siv;
      __builtin_nontemporal_store(o, (f32x4*)(attn_out + ab));
      o.x = __uint_as_float(((unsigned int)raw0.z) << 16) * siv;
      o.y = __uint_as_float(((unsigned int)raw0.z) & 0xffff0000u) * siv;
      o.z = __uint_as_float(((unsigned int)raw0.w) << 16) * siv;
      o.w = __uint_as_float(((unsigned int)raw0.w) & 0xffff0000u) * siv;
      __builtin_nontemporal_store(o, (f32x4*)(attn_out + ab + 4));
      o.x = __uint_as_float(((unsigned int)raw1.x) << 16) * siv;
      o.y = __uint_as_float(((unsigned int)raw1.x) & 0xffff0000u) * siv;
      o.z = __uint_as_float(((unsigned int)raw1.y) << 16) * siv;
      o.w = __uint_as_float(((unsigned int)raw1.y) & 0xffff0000u) * siv;
      __builtin_nontemporal_store(o, (f32x4*)(attn_out + ab + 8));
      o.x = __uint_as_float(((unsigned int)raw1.z) << 16) * siv;
      o.y = __uint_as_float(((unsigned int)raw1.z) & 0xffff0000u) * siv;
      o.z = __uint_as_float(((unsigned int)raw1.w) << 16) * siv;
      o.w = __uint_as_float(((unsigned int)raw1.w) & 0xffff0000u) * siv;
      __builtin_nontemporal_store(o, (f32x4*)(attn_out + ab + 12));
    }
    // PV: pv[mf](d rows = wave slice, m cols) += v^T x e   (unnormalized e)
#pragma unroll
    for (int ks = 0; ks < 2; ++ks) {
      bf16x8 vfk = ks ? vc1 : vc0;
#pragma unroll
      for (int mf = 0; mf < 4; ++mf) {
        bf16x8 ef = *(const bf16x8*)&e_lds[cur][(mf * 16 + l15) * 72 + ks * 32 + l4 * 8];
        pv[mf] = __builtin_amdgcn_mfma_f32_16x16x32_bf16(vfk, ef, pv[mf], 0, 0, 0);
      }
    }
    __syncthreads();
  }

  // epilogue: normalize pv by 1/rowsum[m], write ao (lane has 4 consecutive d)
#pragma unroll
  for (int mf = 0; mf < 4; ++mf) {
    int tok = q0 + mf * 16 + l15;
    int d = w * 16 + l4 * 4;
    float iv = inv_col[mf];
    unsigned int p0 = f2bf(pv[mf][0] * iv) | ((unsigned int)f2bf(pv[mf][1] * iv) << 16);
    unsigned int p1 = f2bf(pv[mf][2] * iv) | ((unsigned int)f2bf(pv[mf][3] * iv) << 16);
    *(uint2*)(ao_ws + ((size_t)(b * 2048 + tok)) * 1024 + h * 64 + d) = make_uint2(p0, p1);
  }
}

// ---- K3: out = ao @ woutb^T + b_out (M=4096, N=1024, K=1024) ----
__global__ __launch_bounds__(256) void gemm_out(
    const unsigned short* __restrict__ AO, const unsigned short* __restrict__ WB,
    const float* __restrict__ Bias, float* __restrict__ OUT) {
  __shared__ unsigned short smem[2 * 128 * 72];
  unsigned short* a_lds = smem;
  unsigned short* b_lds = smem + 128 * 72;
  const int tid = threadIdx.x;
  const int lane = tid & 63;
  const int wid = tid >> 6;
  const int wm = wid >> 1, wn = wid & 1;
  const int m0 = blockIdx.x * 128, n0 = blockIdx.y * 128;

  f32x4 acc[4][4];
#pragma unroll
  for (int i = 0; i < 4; ++i)
#pragma unroll
    for (int j = 0; j < 4; ++j) acc[i][j] = (f32x4){0.f, 0.f, 0.f, 0.f};

  for (int kt = 0; kt < 16; ++kt) {
    const int k0 = kt * 64;
#pragma unroll
    for (int i = 0; i < 4; ++i) {
      int c = i * 256 + tid;
      int row = c >> 3, cc = (c & 7) << 3;
      *(int4*)&a_lds[row * 72 + cc] = *(const int4*)(AO + (size_t)(m0 + row) * 1024 + k0 + cc);
      *(int4*)&b_lds[row * 72 + cc] = *(const int4*)(WB + (size_t)(n0 + row) * 1024 + k0 + cc);
    }
    __syncthreads();
#pragma unroll
    for (int ks = 0; ks < 2; ++ks) {
      bf16x8 af[4], bfr[4];
#pragma unroll
      for (int f = 0; f < 4; ++f) {
        af[f]  = *(const bf16x8*)&a_lds[(wm * 64 + f * 16 + (lane & 15)) * 72 + ks * 32 + (lane >> 4) * 8];
        bfr[f] = *(const bf16x8*)&b_lds[(wn * 64 + f * 16 + (lane & 15)) * 72 + ks * 32 + (lane >> 4) * 8];
      }
#pragma unroll
      for (int fi = 0; fi < 4; ++fi)
#pragma unroll
        for (int fj = 0; fj < 4; ++fj)
          acc[fi][fj] = __builtin_amdgcn_mfma_f32_16x16x32_bf16(af[fi], bfr[fj], acc[fi][fj], 0, 0, 0);
    }
    __syncthreads();
  }

  float* ftile = (float*)smem;
#pragma unroll
  for (int half = 0; half < 2; ++half) {
    if (wm == half) {
#pragma unroll
      for (int fi = 0; fi < 4; ++fi)
#pragma unroll
        for (int fj = 0; fj < 4; ++fj) {
          int row = fi * 16 + ((lane >> 4) << 2);
          int col = wn * 64 + fj * 16 + (lane & 15);
#pragma unroll
          for (int r = 0; r < 4; ++r) ftile[(row + r) * 136 + col] = acc[fi][fj][r];
        }
    }
    __syncthreads();
#pragma unroll
    for (int i = 0; i < 8; ++i) {
      int c = i * 256 + tid;
      int row = c >> 5, cc = c & 31;
      float4 v = *(const float4*)&ftile[row * 136 + cc * 4];
      float4 bb = *(const float4*)(Bias + n0 + cc * 4);
      v.x += bb.x; v.y += bb.y; v.z += bb.z; v.w += bb.w;
      *(float4*)(OUT + (size_t)(m0 + half * 64 + row) * 1024 + n0 + cc * 4) = v;
    }
    __syncthreads();
  }
}

extern "C" void kernel_launch(void* const* d_in, const int* in_sizes, int n_in,
                              void* d_out, int out_size, void* d_ws, size_t ws_size,
                              hipStream_t stream) {
  const float* x     = (const float*)d_in[0];
  const float* w_qkv = (const float*)d_in[1];
  const float* w_out = (const float*)d_in[2];
  const float* b_out = (const float*)d_in[3];

  float* out      = (float*)d_out;
  float* attn_out = out + (size_t)4096 * 1024;

  unsigned short* qk_ws = (unsigned short*)d_ws;
  unsigned short* vt_ws = qk_ws + (size_t)4096 * 2048;
  unsigned short* ao_ws = vt_ws + (size_t)32 * 64 * 2048;
  unsigned short* xb    = ao_ws + (size_t)4096 * 1024;
  unsigned short* wqkvb = xb + (size_t)4096 * 1024;
  unsigned short* woutb = wqkvb + (size_t)3072 * 1024;

  conv_bf16<<<4096, 256, 0, stream>>>(x, w_qkv, w_out, xb, wqkvb, woutb);
  gemm_qkv<<<dim3(32, 24), 256, 0, stream>>>(xb, wqkvb, qk_ws, vt_ws);
  attn_fused<<<dim3(32, 32), 256, 0, stream>>>(qk_ws, vt_ws, attn_out, ao_ws);
  gemm_out<<<dim3(32, 8), 256, 0, stream>>>(ao_ws, woutb, b_out, out);
}

// Round 11
// 857.923 us; speedup vs baseline: 1.4707x; 1.4707x over previous
//
#include <hip/hip_runtime.h>

// B=2, L=2048, E=1024, H=16, d=64.
// d_out: out [4096][1024] fp32, attn [32][2048][2048] fp32.
// Workspace layout (prefix shared by both paths):
//   qk_ws bf16[4096][2048] | vt_ws bf16[32][64][2048] | ao_ws bf16[4096][1024] |
//   xb bf16[4096][1024] | wqkvb bf16[3072][1024] | woutb bf16[1024][1024] |
//   rs_ws f32[32*2048] | e_ws bf16[32][2048][2048]  (fast path only, +256 MB)

typedef __attribute__((ext_vector_type(8))) short bf16x8;
typedef __attribute__((ext_vector_type(4))) float f32x4;

__device__ __forceinline__ unsigned short f2bf(float f) {
  unsigned int u = __float_as_uint(f);
  u += 0x7fffu + ((u >> 16) & 1u);   // RNE
  return (unsigned short)(u >> 16);
}

// ---- K0: one-shot fp32 -> bf16 conversion of x, w_qkv, w_out ----
__global__ __launch_bounds__(256) void conv_bf16(
    const float* __restrict__ X, const float* __restrict__ Wqkv, const float* __restrict__ Wout,
    unsigned short* __restrict__ xb, unsigned short* __restrict__ wqkvb,
    unsigned short* __restrict__ woutb) {
  size_t e0 = ((size_t)blockIdx.x * 256 + threadIdx.x) * 8;
  const float* src; unsigned short* dst; size_t off;
  if (e0 < 4194304)      { src = X;    dst = xb;    off = e0; }
  else if (e0 < 7340032) { src = Wqkv; dst = wqkvb; off = e0 - 4194304; }
  else                   { src = Wout; dst = woutb; off = e0 - 7340032; }
  float4 a = *(const float4*)(src + off);
  float4 c = *(const float4*)(src + off + 4);
  int4 o;
  o.x = f2bf(a.x) | ((unsigned int)f2bf(a.y) << 16);
  o.y = f2bf(a.z) | ((unsigned int)f2bf(a.w) << 16);
  o.z = f2bf(c.x) | ((unsigned int)f2bf(c.y) << 16);
  o.w = f2bf(c.z) | ((unsigned int)f2bf(c.w) << 16);
  *(int4*)(dst + off) = o;
}

// ---- K1: qkv = xb @ wqkvb^T (M=4096, N=3072, K=1024) ----
__global__ __launch_bounds__(256) void gemm_qkv(
    const unsigned short* __restrict__ XB, const unsigned short* __restrict__ WB,
    unsigned short* __restrict__ qk_ws, unsigned short* __restrict__ vt_ws) {
  __shared__ unsigned short smem[2 * 128 * 72];
  unsigned short* a_lds = smem;
  unsigned short* b_lds = smem + 128 * 72;
  const int tid = threadIdx.x;
  const int lane = tid & 63;
  const int wid = tid >> 6;
  const int wm = wid >> 1, wn = wid & 1;
  const int m0 = blockIdx.x * 128;
  const int n0 = blockIdx.y * 128;

  f32x4 acc[4][4];
#pragma unroll
  for (int i = 0; i < 4; ++i)
#pragma unroll
    for (int j = 0; j < 4; ++j) acc[i][j] = (f32x4){0.f, 0.f, 0.f, 0.f};

  for (int kt = 0; kt < 16; ++kt) {
    const int k0 = kt * 64;
#pragma unroll
    for (int i = 0; i < 4; ++i) {
      int c = i * 256 + tid;
      int row = c >> 3, cc = (c & 7) << 3;
      *(int4*)&a_lds[row * 72 + cc] = *(const int4*)(XB + (size_t)(m0 + row) * 1024 + k0 + cc);
      *(int4*)&b_lds[row * 72 + cc] = *(const int4*)(WB + (size_t)(n0 + row) * 1024 + k0 + cc);
    }
    __syncthreads();
#pragma unroll
    for (int ks = 0; ks < 2; ++ks) {
      bf16x8 af[4], bfr[4];
#pragma unroll
      for (int f = 0; f < 4; ++f) {
        af[f]  = *(const bf16x8*)&a_lds[(wm * 64 + f * 16 + (lane & 15)) * 72 + ks * 32 + (lane >> 4) * 8];
        bfr[f] = *(const bf16x8*)&b_lds[(wn * 64 + f * 16 + (lane & 15)) * 72 + ks * 32 + (lane >> 4) * 8];
      }
#pragma unroll
      for (int fi = 0; fi < 4; ++fi)
#pragma unroll
        for (int fj = 0; fj < 4; ++fj)
          acc[fi][fj] = __builtin_amdgcn_mfma_f32_16x16x32_bf16(af[fi], bfr[fj], acc[fi][fj], 0, 0, 0);
    }
    __syncthreads();
  }

  if (n0 < 2048) {
#pragma unroll
    for (int fi = 0; fi < 4; ++fi)
#pragma unroll
      for (int fj = 0; fj < 4; ++fj) {
        int row = wm * 64 + fi * 16 + ((lane >> 4) << 2);
        int col = wn * 64 + fj * 16 + (lane & 15);
#pragma unroll
        for (int r = 0; r < 4; ++r) smem[(row + r) * 136 + col] = f2bf(acc[fi][fj][r]);
      }
    __syncthreads();
#pragma unroll
    for (int i = 0; i < 8; ++i) {
      int c = i * 256 + tid;
      int row = c >> 4, cc = c & 15;
      *(int4*)(qk_ws + (size_t)(m0 + row) * 2048 + n0 + cc * 8) = *(const int4*)&smem[row * 136 + cc * 8];
    }
  } else {
#pragma unroll
    for (int fi = 0; fi < 4; ++fi)
#pragma unroll
      for (int fj = 0; fj < 4; ++fj) {
        int colg = n0 - 2048 + wn * 64 + fj * 16 + (lane & 15);
        int tok = m0 + wm * 64 + fi * 16 + ((lane >> 4) << 2);
        int bb = tok >> 11, lt = tok & 2047;
        int bh = bb * 16 + (colg >> 6);
        int dd = colg & 63;
        unsigned int p0 = f2bf(acc[fi][fj][0]) | ((unsigned int)f2bf(acc[fi][fj][1]) << 16);
        unsigned int p1 = f2bf(acc[fi][fj][2]) | ((unsigned int)f2bf(acc[fi][fj][3]) << 16);
        *(uint2*)(vt_ws + (size_t)(bh * 64 + dd) * 2048 + lt) = make_uint2(p0, p1);
      }
  }
}

// ---- K2 (fast path): single-pass attention. QBLK=32, grid 2048 blocks.
// Stores unnormalized e (bf16) to e_ws, accumulates rowsum + PV, writes 1/rowsum + ao.
__global__ __launch_bounds__(256) void attn_pass(
    const unsigned short* __restrict__ qk_ws, const unsigned short* __restrict__ vt_ws,
    unsigned short* __restrict__ e_ws, float* __restrict__ rs_ws,
    unsigned short* __restrict__ ao_ws) {
  __shared__ unsigned short e_lds[2][32 * 72];
  __shared__ float ls_rs[32];
  __shared__ float ls_inv[32];

  const int tid = threadIdx.x;
  const int lane = tid & 63;
  const int w = tid >> 6;
  const int l15 = lane & 15;
  const int l4 = lane >> 4;
  const int bh = blockIdx.y;
  const int b = bh >> 4;
  const int h = bh & 15;
  const int q0 = blockIdx.x * 32;

  // K: row j = jt*64 + w*16 + l15, d-slice = ks*32 + l4*8
  const unsigned short* kp = qk_ws + ((size_t)(b * 2048 + w * 16 + l15)) * 2048 + 1024 + h * 64 + l4 * 8;
  const size_t KJ = (size_t)64 * 2048;
  // V^T: row d = w*16 + l15, j-slice = jt*64 + ks*32 + l4*8
  const unsigned short* vp = vt_ws + ((size_t)(bh * 64 + w * 16 + l15)) * 2048 + l4 * 8;

  bf16x8 qf[2][2];
#pragma unroll
  for (int fi = 0; fi < 2; ++fi)
#pragma unroll
    for (int ks = 0; ks < 2; ++ks)
      qf[fi][ks] = *(const bf16x8*)(qk_ws + ((size_t)(b * 2048 + q0 + fi * 16 + l15)) * 2048 + h * 64 + ks * 32 + l4 * 8);

  if (tid < 32) ls_rs[tid] = 0.f;

  float ps[2][4] = {{0.f, 0.f, 0.f, 0.f}, {0.f, 0.f, 0.f, 0.f}};
  f32x4 pv[2];
  pv[0] = (f32x4){0.f, 0.f, 0.f, 0.f};
  pv[1] = (f32x4){0.f, 0.f, 0.f, 0.f};

  const int srow = tid >> 3;            // e store: 8 threads/row, int4 each
  const int sc0 = (tid & 7) << 3;
  unsigned short* ep = e_ws + ((size_t)bh * 2048 + q0 + srow) * 2048 + sc0;

  bf16x8 kn0 = *(const bf16x8*)(kp);
  bf16x8 kn1 = *(const bf16x8*)(kp + 32);
  bf16x8 vn0 = *(const bf16x8*)(vp);
  bf16x8 vn1 = *(const bf16x8*)(vp + 32);

  for (int jt = 0; jt < 32; ++jt) {
    const int cur = jt & 1;
    bf16x8 kc0 = kn0, kc1 = kn1, vc0 = vn0, vc1 = vn1;
    if (jt + 1 < 32) {
      kn0 = *(const bf16x8*)(kp + (jt + 1) * KJ);
      kn1 = *(const bf16x8*)(kp + (jt + 1) * KJ + 32);
      vn0 = *(const bf16x8*)(vp + (jt + 1) * 64);
      vn1 = *(const bf16x8*)(vp + (jt + 1) * 64 + 32);
    }
    f32x4 s[2];
#pragma unroll
    for (int fi = 0; fi < 2; ++fi) {
      s[fi] = (f32x4){0.f, 0.f, 0.f, 0.f};
      s[fi] = __builtin_amdgcn_mfma_f32_16x16x32_bf16(qf[fi][0], kc0, s[fi], 0, 0, 0);
      s[fi] = __builtin_amdgcn_mfma_f32_16x16x32_bf16(qf[fi][1], kc1, s[fi], 0, 0, 0);
    }
    // exp, rowsum accumulate, e -> LDS (unnormalized)
#pragma unroll
    for (int fi = 0; fi < 2; ++fi) {
      int row0 = fi * 16 + l4 * 4;
      int col = w * 16 + l15;
#pragma unroll
      for (int r = 0; r < 4; ++r) {
        float e = __expf(s[fi][r] * 0.125f);
        ps[fi][r] += e;
        e_lds[cur][(row0 + r) * 72 + col] = f2bf(e);
      }
    }
    __syncthreads();
    // coalesced bf16 e-tile store (32x64): 4 KB/block-iter
    *(int4*)(ep + jt * 64) = *(const int4*)&e_lds[cur][srow * 72 + sc0];
    // PV: pv[mf](d = wave slice, m cols) += v^T x e
#pragma unroll
    for (int ks = 0; ks < 2; ++ks) {
      bf16x8 vfk = ks ? vc1 : vc0;
#pragma unroll
      for (int mf = 0; mf < 2; ++mf) {
        bf16x8 ef = *(const bf16x8*)&e_lds[cur][(mf * 16 + l15) * 72 + ks * 32 + l4 * 8];
        pv[mf] = __builtin_amdgcn_mfma_f32_16x16x32_bf16(vfk, ef, pv[mf], 0, 0, 0);
      }
    }
    // single barrier per iter: double buffer makes write(jt+2) safe after barrier(jt+1)
  }

  // rowsum reduce: 16 lanes (l15) per q-row, then across waves
#pragma unroll
  for (int fi = 0; fi < 2; ++fi)
#pragma unroll
    for (int r = 0; r < 4; ++r) {
      float v = ps[fi][r];
      v += __shfl_xor(v, 1);
      v += __shfl_xor(v, 2);
      v += __shfl_xor(v, 4);
      v += __shfl_xor(v, 8);
      if (l15 == 0) atomicAdd(&ls_rs[fi * 16 + l4 * 4 + r], v);
    }
  __syncthreads();
  if (tid < 32) {
    float iv = 1.0f / ls_rs[tid];
    ls_inv[tid] = iv;
    rs_ws[(size_t)bh * 2048 + q0 + tid] = iv;
  }
  __syncthreads();

#pragma unroll
  for (int mf = 0; mf < 2; ++mf) {
    float iv = ls_inv[mf * 16 + l15];
    int tok = q0 + mf * 16 + l15;
    int d = w * 16 + l4 * 4;
    unsigned int p0 = f2bf(pv[mf][0] * iv) | ((unsigned int)f2bf(pv[mf][1] * iv) << 16);
    unsigned int p1 = f2bf(pv[mf][2] * iv) | ((unsigned int)f2bf(pv[mf][3] * iv) << 16);
    *(uint2*)(ao_ws + ((size_t)(b * 2048 + tok)) * 1024 + h * 64 + d) = make_uint2(p0, p1);
  }
}

// ---- K2b (fast path): pure streaming normalize: attn = bf16(e) * inv[row], fp32 NT ----
__global__ __launch_bounds__(256) void normalize_attn(
    const unsigned short* __restrict__ e_ws, const float* __restrict__ rs_ws,
    float* __restrict__ attn_out) {
  const size_t stride = (size_t)gridDim.x * 256;
  for (size_t g = (size_t)blockIdx.x * 256 + threadIdx.x; g < 16777216u; g += stride) {
    size_t e0 = g * 8;
    float iv = rs_ws[e0 >> 11];
    int4 raw = *(const int4*)(e_ws + e0);
    f32x4 o0, o1;
    o0.x = __uint_as_float(((unsigned int)raw.x) << 16) * iv;
    o0.y = __uint_as_float(((unsigned int)raw.x) & 0xffff0000u) * iv;
    o0.z = __uint_as_float(((unsigned int)raw.y) << 16) * iv;
    o0.w = __uint_as_float(((unsigned int)raw.y) & 0xffff0000u) * iv;
    o1.x = __uint_as_float(((unsigned int)raw.z) << 16) * iv;
    o1.y = __uint_as_float(((unsigned int)raw.z) & 0xffff0000u) * iv;
    o1.z = __uint_as_float(((unsigned int)raw.w) << 16) * iv;
    o1.w = __uint_as_float(((unsigned int)raw.w) & 0xffff0000u) * iv;
    __builtin_nontemporal_store(o0, (f32x4*)(attn_out + e0));
    __builtin_nontemporal_store(o1, (f32x4*)(attn_out + e0 + 4));
  }
}

// ---- K2 (fallback, small ws): two-phase attention writing fp32 directly ----
__global__ __launch_bounds__(256) void attn_fused(
    const unsigned short* __restrict__ qk_ws, const unsigned short* __restrict__ vt_ws,
    float* __restrict__ attn_out, unsigned short* __restrict__ ao_ws) {
  __shared__ unsigned short e_lds[2][64 * 72];
  __shared__ float ls_rs[64];
  __shared__ float ls_inv[64];

  const int tid = threadIdx.x;
  const int lane = tid & 63;
  const int w = tid >> 6;
  const int l15 = lane & 15;
  const int l4 = lane >> 4;
  const int bh = blockIdx.y;
  const int b = bh >> 4;
  const int h = bh & 15;
  const int q0 = blockIdx.x * 64;

  const unsigned short* kp = qk_ws + ((size_t)(b * 2048 + w * 16 + l15)) * 2048 + 1024 + h * 64 + l4 * 8;
  const size_t KJ = (size_t)64 * 2048;
  const unsigned short* vp = vt_ws + ((size_t)(bh * 64 + w * 16 + l15)) * 2048 + l4 * 8;

  bf16x8 qf[4][2];
#pragma unroll
  for (int fi = 0; fi < 4; ++fi)
#pragma unroll
    for (int ks = 0; ks < 2; ++ks)
      qf[fi][ks] = *(const bf16x8*)(qk_ws + ((size_t)(b * 2048 + q0 + fi * 16 + l15)) * 2048 + h * 64 + ks * 32 + l4 * 8);

  float ps[4][4];
#pragma unroll
  for (int fi = 0; fi < 4; ++fi)
#pragma unroll
    for (int r = 0; r < 4; ++r) ps[fi][r] = 0.f;

  bf16x8 kn0 = *(const bf16x8*)(kp);
  bf16x8 kn1 = *(const bf16x8*)(kp + 32);
  for (int jt = 0; jt < 32; ++jt) {
    bf16x8 kc0 = kn0, kc1 = kn1;
    if (jt + 1 < 32) {
      kn0 = *(const bf16x8*)(kp + (jt + 1) * KJ);
      kn1 = *(const bf16x8*)(kp + (jt + 1) * KJ + 32);
    }
    f32x4 s[4];
#pragma unroll
    for (int fi = 0; fi < 4; ++fi) {
      s[fi] = (f32x4){0.f, 0.f, 0.f, 0.f};
      s[fi] = __builtin_amdgcn_mfma_f32_16x16x32_bf16(qf[fi][0], kc0, s[fi], 0, 0, 0);
      s[fi] = __builtin_amdgcn_mfma_f32_16x16x32_bf16(qf[fi][1], kc1, s[fi], 0, 0, 0);
    }
#pragma unroll
    for (int fi = 0; fi < 4; ++fi)
#pragma unroll
      for (int r = 0; r < 4; ++r) ps[fi][r] += __expf(s[fi][r] * 0.125f);
  }

  if (tid < 64) ls_rs[tid] = 0.f;
  __syncthreads();
#pragma unroll
  for (int fi = 0; fi < 4; ++fi)
#pragma unroll
    for (int r = 0; r < 4; ++r) {
      float v = ps[fi][r];
      v += __shfl_xor(v, 1);
      v += __shfl_xor(v, 2);
      v += __shfl_xor(v, 4);
      v += __shfl_xor(v, 8);
      if (l15 == 0) atomicAdd(&ls_rs[fi * 16 + l4 * 4 + r], v);
    }
  __syncthreads();
  if (tid < 64) ls_inv[tid] = 1.0f / ls_rs[tid];
  __syncthreads();
  float inv_col[4];
#pragma unroll
  for (int mf = 0; mf < 4; ++mf) inv_col[mf] = ls_inv[mf * 16 + l15];

  f32x4 pv[4];
#pragma unroll
  for (int mf = 0; mf < 4; ++mf) pv[mf] = (f32x4){0.f, 0.f, 0.f, 0.f};

  const int srow = tid >> 2;
  const int sc0 = (tid & 3) << 4;
  const float siv = ls_inv[srow];

  kn0 = *(const bf16x8*)(kp);
  kn1 = *(const bf16x8*)(kp + 32);
  bf16x8 vn0 = *(const bf16x8*)(vp);
  bf16x8 vn1 = *(const bf16x8*)(vp + 32);
  for (int jt = 0; jt < 32; ++jt) {
    const int cur = jt & 1;
    bf16x8 kc0 = kn0, kc1 = kn1, vc0 = vn0, vc1 = vn1;
    if (jt + 1 < 32) {
      kn0 = *(const bf16x8*)(kp + (jt + 1) * KJ);
      kn1 = *(const bf16x8*)(kp + (jt + 1) * KJ + 32);
      vn0 = *(const bf16x8*)(vp + (jt + 1) * 64);
      vn1 = *(const bf16x8*)(vp + (jt + 1) * 64 + 32);
    }
    f32x4 s[4];
#pragma unroll
    for (int fi = 0; fi < 4; ++fi) {
      s[fi] = (f32x4){0.f, 0.f, 0.f, 0.f};
      s[fi] = __builtin_amdgcn_mfma_f32_16x16x32_bf16(qf[fi][0], kc0, s[fi], 0, 0, 0);
      s[fi] = __builtin_amdgcn_mfma_f32_16x16x32_bf16(qf[fi][1], kc1, s[fi], 0, 0, 0);
    }
#pragma unroll
    for (int fi = 0; fi < 4; ++fi) {
      int row0 = fi * 16 + l4 * 4;
      int col = w * 16 + l15;
#pragma unroll
      for (int r = 0; r < 4; ++r)
        e_lds[cur][(row0 + r) * 72 + col] = f2bf(__expf(s[fi][r] * 0.125f));
    }
    __syncthreads();
    {
      int4 raw0 = *(const int4*)&e_lds[cur][srow * 72 + sc0];
      int4 raw1 = *(const int4*)&e_lds[cur][srow * 72 + sc0 + 8];
      size_t ab = ((size_t)bh * 2048 + q0 + srow) * 2048 + jt * 64 + sc0;
      f32x4 o;
      o.x = __uint_as_float(((unsigned int)raw0.x) << 16) * siv;
      o.y = __uint_as_float(((unsigned int)raw0.x) & 0xffff0000u) * siv;
      o.z = __uint_as_float(((unsigned int)raw0.y) << 16) * siv;
      o.w = __uint_as_float(((unsigned int)raw0.y) & 0xffff0000u) * siv;
      __builtin_nontemporal_store(o, (f32x4*)(attn_out + ab));
      o.x = __uint_as_float(((unsigned int)raw0.z) << 16) * siv;
      o.y = __uint_as_float(((unsigned int)raw0.z) & 0xffff0000u) * siv;
      o.z = __uint_as_float(((unsigned int)raw0.w) << 16) * siv;
      o.w = __uint_as_float(((unsigned int)raw0.w) & 0xffff0000u) * siv;
      __builtin_nontemporal_store(o, (f32x4*)(attn_out + ab + 4));
      o.x = __uint_as_float(((unsigned int)raw1.x) << 16) * siv;
      o.y = __uint_as_float(((unsigned int)raw1.x) & 0xffff0000u) * siv;
      o.z = __uint_as_float(((unsigned int)raw1.y) << 16) * siv;
      o.w = __uint_as_float(((unsigned int)raw1.y) & 0xffff0000u) * siv;
      __builtin_nontemporal_store(o, (f32x4*)(attn_out + ab + 8));
      o.x = __uint_as_float(((unsigned int)raw1.z) << 16) * siv;
      o.y = __uint_as_float(((unsigned int)raw1.z) & 0xffff0000u) * siv;
      o.z = __uint_as_float(((unsigned int)raw1.w) << 16) * siv;
      o.w = __uint_as_float(((unsigned int)raw1.w) & 0xffff0000u) * siv;
      __builtin_nontemporal_store(o, (f32x4*)(attn_out + ab + 12));
    }
#pragma unroll
    for (int ks = 0; ks < 2; ++ks) {
      bf16x8 vfk = ks ? vc1 : vc0;
#pragma unroll
      for (int mf = 0; mf < 4; ++mf) {
        bf16x8 ef = *(const bf16x8*)&e_lds[cur][(mf * 16 + l15) * 72 + ks * 32 + l4 * 8];
        pv[mf] = __builtin_amdgcn_mfma_f32_16x16x32_bf16(vfk, ef, pv[mf], 0, 0, 0);
      }
    }
    __syncthreads();
  }

#pragma unroll
  for (int mf = 0; mf < 4; ++mf) {
    int tok = q0 + mf * 16 + l15;
    int d = w * 16 + l4 * 4;
    float iv = inv_col[mf];
    unsigned int p0 = f2bf(pv[mf][0] * iv) | ((unsigned int)f2bf(pv[mf][1] * iv) << 16);
    unsigned int p1 = f2bf(pv[mf][2] * iv) | ((unsigned int)f2bf(pv[mf][3] * iv) << 16);
    *(uint2*)(ao_ws + ((size_t)(b * 2048 + tok)) * 1024 + h * 64 + d) = make_uint2(p0, p1);
  }
}

// ---- K3: out = ao @ woutb^T + b_out (M=4096, N=1024, K=1024) ----
__global__ __launch_bounds__(256) void gemm_out(
    const unsigned short* __restrict__ AO, const unsigned short* __restrict__ WB,
    const float* __restrict__ Bias, float* __restrict__ OUT) {
  __shared__ unsigned short smem[2 * 128 * 72];
  unsigned short* a_lds = smem;
  unsigned short* b_lds = smem + 128 * 72;
  const int tid = threadIdx.x;
  const int lane = tid & 63;
  const int wid = tid >> 6;
  const int wm = wid >> 1, wn = wid & 1;
  const int m0 = blockIdx.x * 128, n0 = blockIdx.y * 128;

  f32x4 acc[4][4];
#pragma unroll
  for (int i = 0; i < 4; ++i)
#pragma unroll
    for (int j = 0; j < 4; ++j) acc[i][j] = (f32x4){0.f, 0.f, 0.f, 0.f};

  for (int kt = 0; kt < 16; ++kt) {
    const int k0 = kt * 64;
#pragma unroll
    for (int i = 0; i < 4; ++i) {
      int c = i * 256 + tid;
      int row = c >> 3, cc = (c & 7) << 3;
      *(int4*)&a_lds[row * 72 + cc] = *(const int4*)(AO + (size_t)(m0 + row) * 1024 + k0 + cc);
      *(int4*)&b_lds[row * 72 + cc] = *(const int4*)(WB + (size_t)(n0 + row) * 1024 + k0 + cc);
    }
    __syncthreads();
#pragma unroll
    for (int ks = 0; ks < 2; ++ks) {
      bf16x8 af[4], bfr[4];
#pragma unroll
      for (int f = 0; f < 4; ++f) {
        af[f]  = *(const bf16x8*)&a_lds[(wm * 64 + f * 16 + (lane & 15)) * 72 + ks * 32 + (lane >> 4) * 8];
        bfr[f] = *(const bf16x8*)&b_lds[(wn * 64 + f * 16 + (lane & 15)) * 72 + ks * 32 + (lane >> 4) * 8];
      }
#pragma unroll
      for (int fi = 0; fi < 4; ++fi)
#pragma unroll
        for (int fj = 0; fj < 4; ++fj)
          acc[fi][fj] = __builtin_amdgcn_mfma_f32_16x16x32_bf16(af[fi], bfr[fj], acc[fi][fj], 0, 0, 0);
    }
    __syncthreads();
  }

  float* ftile = (float*)smem;
#pragma unroll
  for (int half = 0; half < 2; ++half) {
    if (wm == half) {
#pragma unroll
      for (int fi = 0; fi < 4; ++fi)
#pragma unroll
        for (int fj = 0; fj < 4; ++fj) {
          int row = fi * 16 + ((lane >> 4) << 2);
          int col = wn * 64 + fj * 16 + (lane & 15);
#pragma unroll
          for (int r = 0; r < 4; ++r) ftile[(row + r) * 136 + col] = acc[fi][fj][r];
        }
    }
    __syncthreads();
#pragma unroll
    for (int i = 0; i < 8; ++i) {
      int c = i * 256 + tid;
      int row = c >> 5, cc = c & 31;
      float4 v = *(const float4*)&ftile[row * 136 + cc * 4];
      float4 bb = *(const float4*)(Bias + n0 + cc * 4);
      v.x += bb.x; v.y += bb.y; v.z += bb.z; v.w += bb.w;
      *(float4*)(OUT + (size_t)(m0 + half * 64 + row) * 1024 + n0 + cc * 4) = v;
    }
    __syncthreads();
  }
}

extern "C" void kernel_launch(void* const* d_in, const int* in_sizes, int n_in,
                              void* d_out, int out_size, void* d_ws, size_t ws_size,
                              hipStream_t stream) {
  const float* x     = (const float*)d_in[0];
  const float* w_qkv = (const float*)d_in[1];
  const float* w_out = (const float*)d_in[2];
  const float* b_out = (const float*)d_in[3];

  float* out      = (float*)d_out;
  float* attn_out = out + (size_t)4096 * 1024;

  unsigned short* qk_ws = (unsigned short*)d_ws;               // 16 MB
  unsigned short* vt_ws = qk_ws + (size_t)4096 * 2048;         //  8 MB
  unsigned short* ao_ws = vt_ws + (size_t)32 * 64 * 2048;      //  8 MB
  unsigned short* xb    = ao_ws + (size_t)4096 * 1024;         //  8 MB
  unsigned short* wqkvb = xb + (size_t)4096 * 1024;            //  6 MB
  unsigned short* woutb = wqkvb + (size_t)3072 * 1024;         //  2 MB
  float*          rs_ws = (float*)(woutb + (size_t)1024 * 1024);      // 256 KB
  unsigned short* e_ws  = (unsigned short*)(rs_ws + (size_t)32 * 2048); // 256 MB (fast path)
  const size_t WS_NEED_FAST = 319029248ULL;   // prefix (50.6 MB) + e_ws (256 MB)

  conv_bf16<<<4096, 256, 0, stream>>>(x, w_qkv, w_out, xb, wqkvb, woutb);
  gemm_qkv<<<dim3(32, 24), 256, 0, stream>>>(xb, wqkvb, qk_ws, vt_ws);
  if (ws_size >= WS_NEED_FAST) {
    attn_pass<<<dim3(64, 32), 256, 0, stream>>>(qk_ws, vt_ws, e_ws, rs_ws, ao_ws);
    normalize_attn<<<2048, 256, 0, stream>>>(e_ws, rs_ws, attn_out);
  } else {
    attn_fused<<<dim3(32, 32), 256, 0, stream>>>(qk_ws, vt_ws, attn_out, ao_ws);
  }
  gemm_out<<<dim3(32, 8), 256, 0, stream>>>(ao_ws, woutb, b_out, out);
}